// Round 2
// baseline (825.047 us; speedup 1.0000x reference)
//
#include <hip/hip_runtime.h>
#include <hip/hip_bf16.h>

// Fused Comm_OUT pipeline, fully batch-row-parallel (GRU recurrence is per-row).
// 256 blocks x 32 rows, 512 threads (8 waves, gate-aligned column split).
// All GEMMs: mfma_f32_16x16x32_bf16. Weights streamed from global (L2-resident).
// Runtime dtype detection: inputs may be fp32 (per reference) or bf16 (harness
// conversion). A 1-thread prepass kernel classifies and the main kernel
// branches uniformly into the matching template instantiation.

typedef __attribute__((ext_vector_type(8))) short bf16x8;   // 8 x bf16 (4 VGPRs)
typedef __attribute__((ext_vector_type(4))) float f32x4;    // MFMA accumulator

#define MFMA16(a, b, c) __builtin_amdgcn_mfma_f32_16x16x32_bf16((a), (b), (c), 0, 0, 0)

constexpr int F   = 640;
constexpr int H   = 256;
constexpr int LSTEPS = 20;
constexpr int CO  = 32;
constexpr int BM  = 32;    // batch rows per block
constexpr int LDP = 264;   // padded bf16 row stride (528 B: 16B-aligned, conflict-minimal b128 reads)

__device__ __forceinline__ float bf2f(__hip_bfloat16 x) { return __bfloat162float(x); }
__device__ __forceinline__ unsigned short f2bs(float f) {
    __hip_bfloat16 h = __float2bfloat16(f);
    return *reinterpret_cast<unsigned short*>(&h);
}
__device__ __forceinline__ bf16x8 lds8(const unsigned short* p) {
    return *reinterpret_cast<const bf16x8*>(p);
}
__device__ __forceinline__ float sigm(float x) {
    return 1.0f / (1.0f + __expf(-x));
}

// load 8 contiguous elements at `base[off .. off+7]` as a bf16 MFMA fragment
template<bool F32>
__device__ __forceinline__ bf16x8 g8(const void* base, size_t off) {
    if constexpr (!F32) {
        return *reinterpret_cast<const bf16x8*>((const __hip_bfloat16*)base + off);
    } else {
        const float* f = (const float*)base + off;
        float4 lo = *reinterpret_cast<const float4*>(f);
        float4 hi = *reinterpret_cast<const float4*>(f + 4);
        bf16x8 r;
        r[0] = (short)f2bs(lo.x); r[1] = (short)f2bs(lo.y);
        r[2] = (short)f2bs(lo.z); r[3] = (short)f2bs(lo.w);
        r[4] = (short)f2bs(hi.x); r[5] = (short)f2bs(hi.y);
        r[6] = (short)f2bs(hi.z); r[7] = (short)f2bs(hi.w);
        return r;
    }
}

template<bool F32>
__device__ __forceinline__ float ld1(const void* base, int i) {
    if constexpr (!F32) return bf2f(((const __hip_bfloat16*)base)[i]);
    else                return ((const float*)base)[i];
}

// ---------------- dtype detect: v1 (uniform[0.5,1.5], 256 elems) ----------------
__global__ void detect_dtype(const void* v1, int* flag) {
    // If data is bf16, all 8 leading bf16 values lie in [0.5,1.5].
    // If data is fp32, even "bf16" elements are fp32 mantissa bits -> far out of range.
    const unsigned short* u = (const unsigned short*)v1;
    int f32 = 0;
    for (int i = 0; i < 8; ++i) {
        unsigned short s = u[i];
        __hip_bfloat16 h = *reinterpret_cast<__hip_bfloat16*>(&s);
        float v = __bfloat162float(h);
        if (!(v >= 0.25f && v <= 2.0f)) f32 = 1;
    }
    *flag = f32;
}

template<bool F32>
__device__ __forceinline__ void pipeline(
    const void* hw,
    const void* Wlin, const void* blin,
    const void* g1,   const void* be1, const void* m1, const void* v1, const void* a1,
    const void* Wih,  const void* Whh, const void* bih, const void* bhh,
    const void* g2,   const void* be2, const void* m2, const void* v2, const void* a2,
    const void* Wc,   const void* bc,
    const void* g3,   const void* be3, const void* m3, const void* v3, const void* a3,
    const void* Wmu,  const void* bmu,
    void* out,
    unsigned short* h_lds, unsigned short* u_lds)
{
    const int tid  = threadIdx.x;
    const int w    = tid >> 6;        // wave 0..7
    const int lane = tid & 63;
    const int m16  = lane & 15;
    const int q    = lane >> 4;       // quad 0..3
    const int row0 = blockIdx.x * BM;

    // per-lane columns (C/D layout): wave w owns cols [w*32, w*32+32) of each 256-wide slice
    const int c0 = w * 32 + m16;
    const int c1 = c0 + 16;
    const int cc2[2] = { c0, c1 };

    // ---- per-lane parameter preloads (fold BN to scale/shift) ----
    float s1v[2], t1v[2], s2v[2], t2v[2], s3v[2], t3v[2];
    float blv[2], bihv[3][2], bhhv[3][2], bcv[2];
    #pragma unroll
    for (int j = 0; j < 2; ++j) {
        const int cc = cc2[j];
        float s;
        s = ld1<F32>(g1, cc) * rsqrtf(ld1<F32>(v1, cc) + 1e-5f);
        s1v[j] = s; t1v[j] = ld1<F32>(be1, cc) - ld1<F32>(m1, cc) * s;
        s = ld1<F32>(g2, cc) * rsqrtf(ld1<F32>(v2, cc) + 1e-5f);
        s2v[j] = s; t2v[j] = ld1<F32>(be2, cc) - ld1<F32>(m2, cc) * s;
        s = ld1<F32>(g3, cc) * rsqrtf(ld1<F32>(v3, cc) + 1e-5f);
        s3v[j] = s; t3v[j] = ld1<F32>(be3, cc) - ld1<F32>(m3, cc) * s;
        blv[j] = ld1<F32>(blin, cc);
        bcv[j] = ld1<F32>(bc, cc);
        #pragma unroll
        for (int g = 0; g < 3; ++g) {
            bihv[g][j] = ld1<F32>(bih, g * H + cc);
            bhhv[g][j] = ld1<F32>(bhh, g * H + cc);
        }
    }
    const float a1v = ld1<F32>(a1, 0), a2v = ld1<F32>(a2, 0), a3v = ld1<F32>(a3, 0);

    // ---- Phase 1: x = prelu(bn1(hw_rows @ Wlin^T + blin)) -> u_lds (bf16) ----
    {
        f32x4 acc[2][2] = {};
        const size_t A0 = (size_t)(row0 + m16) * F + q * 8;
        const size_t A1 = A0 + (size_t)16 * F;
        const size_t B0 = (size_t)c0 * F + q * 8;
        const size_t B1 = (size_t)c1 * F + q * 8;
        #pragma unroll 4
        for (int kk = 0; kk < F / 32; ++kk) {
            bf16x8 a0 = g8<F32>(hw, A0 + kk * 32);
            bf16x8 a1f = g8<F32>(hw, A1 + kk * 32);
            bf16x8 b0 = g8<F32>(Wlin, B0 + kk * 32);
            bf16x8 b1 = g8<F32>(Wlin, B1 + kk * 32);
            acc[0][0] = MFMA16(a0, b0, acc[0][0]);
            acc[1][0] = MFMA16(a1f, b0, acc[1][0]);
            acc[0][1] = MFMA16(a0, b1, acc[0][1]);
            acc[1][1] = MFMA16(a1f, b1, acc[1][1]);
        }
        #pragma unroll
        for (int mt = 0; mt < 2; ++mt)
            #pragma unroll
            for (int j = 0; j < 2; ++j)
                #pragma unroll
                for (int r = 0; r < 4; ++r) {
                    float vv = acc[mt][j][r] + blv[j];
                    vv = vv * s1v[j] + t1v[j];
                    vv = (vv >= 0.0f) ? vv : a1v * vv;
                    u_lds[(mt * 16 + q * 4 + r) * LDP + cc2[j]] = f2bs(vv);
                }
    }
    __syncthreads();

    // ---- Phase 2: gi = x @ Wih^T + bih  (stays in registers, C-layout) ----
    f32x4 gi[2][3][2] = {};
    {
        const unsigned short* xa0 = u_lds + m16 * LDP + q * 8;
        const unsigned short* xa1 = xa0 + 16 * LDP;
        size_t Bp[3][2];
        #pragma unroll
        for (int g = 0; g < 3; ++g)
            #pragma unroll
            for (int j = 0; j < 2; ++j)
                Bp[g][j] = (size_t)(g * H + cc2[j]) * H + q * 8;
        #pragma unroll
        for (int kk = 0; kk < H / 32; ++kk) {
            bf16x8 a0 = lds8(xa0 + kk * 32);
            bf16x8 a1f = lds8(xa1 + kk * 32);
            #pragma unroll
            for (int g = 0; g < 3; ++g)
                #pragma unroll
                for (int j = 0; j < 2; ++j) {
                    bf16x8 b = g8<F32>(Wih, Bp[g][j] + kk * 32);
                    gi[0][g][j] = MFMA16(a0, b, gi[0][g][j]);
                    gi[1][g][j] = MFMA16(a1f, b, gi[1][g][j]);
                }
        }
        #pragma unroll
        for (int mt = 0; mt < 2; ++mt)
            #pragma unroll
            for (int g = 0; g < 3; ++g)
                #pragma unroll
                for (int j = 0; j < 2; ++j)
                    #pragma unroll
                    for (int r = 0; r < 4; ++r)
                        gi[mt][g][j][r] += bihv[g][j];
    }

    // ---- GRU loop + fused downstream, per step ----
    float hreg[2][2][4] = {};
    const unsigned short* ha0 = h_lds + m16 * LDP + q * 8;
    const unsigned short* ha1 = ha0 + 16 * LDP;
    const unsigned short* ua0 = u_lds + m16 * LDP + q * 8;
    const unsigned short* ua1 = ua0 + 16 * LDP;
    size_t WhhP[3][2];
    #pragma unroll
    for (int g = 0; g < 3; ++g)
        #pragma unroll
        for (int j = 0; j < 2; ++j)
            WhhP[g][j] = (size_t)(g * H + cc2[j]) * H + q * 8;
    size_t WcP[2];
    #pragma unroll
    for (int j = 0; j < 2; ++j)
        WcP[j] = (size_t)cc2[j] * H + q * 8;

    // out-head assignment: waves 0..3 each own one 16x16 C-tile of the [32,32] result
    const int mto = (w >> 1) & 1;
    const int nto = w & 1;
    const size_t WmuP = (size_t)(nto * 16 + m16) * H + q * 8;
    const float bmuv = (w < 4) ? ld1<F32>(bmu, nto * 16 + m16) : 0.0f;
    const size_t outBase = (size_t)(row0 + mto * 16 + q * 4) * (LSTEPS * CO) + nto * 16 + m16;
    const unsigned short* za = u_lds + (mto * 16 + m16) * LDP + q * 8;

    #pragma unroll 1
    for (int t = 0; t < LSTEPS; ++t) {
        // gh = h @ Whh^T  (t=0: h=0 -> skip)
        f32x4 gh[2][3][2] = {};
        if (t > 0) {
            #pragma unroll
            for (int kk = 0; kk < H / 32; ++kk) {
                bf16x8 a0 = lds8(ha0 + kk * 32);
                bf16x8 a1f = lds8(ha1 + kk * 32);
                #pragma unroll
                for (int g = 0; g < 3; ++g)
                    #pragma unroll
                    for (int j = 0; j < 2; ++j) {
                        bf16x8 b = g8<F32>(Whh, WhhP[g][j] + kk * 32);
                        gh[0][g][j] = MFMA16(a0, b, gh[0][g][j]);
                        gh[1][g][j] = MFMA16(a1f, b, gh[1][g][j]);
                    }
            }
        }
        // gates + h update + y = prelu(bn2(h))   (pure per-lane register math)
        float yv[2][2][4];
        #pragma unroll
        for (int mt = 0; mt < 2; ++mt)
            #pragma unroll
            for (int j = 0; j < 2; ++j)
                #pragma unroll
                for (int r = 0; r < 4; ++r) {
                    float rr = sigm(gi[mt][0][j][r] + gh[mt][0][j][r] + bhhv[0][j]);
                    float zz = sigm(gi[mt][1][j][r] + gh[mt][1][j][r] + bhhv[1][j]);
                    float nin = gi[mt][2][j][r] + rr * (gh[mt][2][j][r] + bhhv[2][j]);
                    float nn = 2.0f * sigm(2.0f * nin) - 1.0f;   // tanh
                    float hh = (1.0f - zz) * nn + zz * hreg[mt][j][r];
                    hreg[mt][j][r] = hh;
                    float y = hh * s2v[j] + t2v[j];
                    yv[mt][j][r] = (y >= 0.0f) ? y : a2v * y;
                }
        __syncthreads();   // A: all waves done reading h_lds (gh) and u_lds (prev out-head)
        #pragma unroll
        for (int mt = 0; mt < 2; ++mt)
            #pragma unroll
            for (int j = 0; j < 2; ++j)
                #pragma unroll
                for (int r = 0; r < 4; ++r) {
                    const int idx = (mt * 16 + q * 4 + r) * LDP + cc2[j];
                    h_lds[idx] = f2bs(hreg[mt][j][r]);
                    u_lds[idx] = f2bs(yv[mt][j][r]);
                }
        __syncthreads();   // B: h/y visible

        // w2 = y @ Wc^T
        f32x4 w2[2][2] = {};
        #pragma unroll
        for (int kk = 0; kk < H / 32; ++kk) {
            bf16x8 a0 = lds8(ua0 + kk * 32);
            bf16x8 a1f = lds8(ua1 + kk * 32);
            #pragma unroll
            for (int j = 0; j < 2; ++j) {
                bf16x8 b = g8<F32>(Wc, WcP[j] + kk * 32);
                w2[0][j] = MFMA16(a0, b, w2[0][j]);
                w2[1][j] = MFMA16(a1f, b, w2[1][j]);
            }
        }
        float zv[2][2][4];
        #pragma unroll
        for (int mt = 0; mt < 2; ++mt)
            #pragma unroll
            for (int j = 0; j < 2; ++j)
                #pragma unroll
                for (int r = 0; r < 4; ++r) {
                    float z0 = (w2[mt][j][r] + bcv[j]) * s3v[j] + t3v[j];
                    zv[mt][j][r] = (z0 >= 0.0f) ? z0 : a3v * z0;
                }
        __syncthreads();   // C: all waves done reading y from u_lds
        #pragma unroll
        for (int mt = 0; mt < 2; ++mt)
            #pragma unroll
            for (int j = 0; j < 2; ++j)
                #pragma unroll
                for (int r = 0; r < 4; ++r)
                    u_lds[(mt * 16 + q * 4 + r) * LDP + cc2[j]] = f2bs(zv[mt][j][r]);
        __syncthreads();   // D: z visible

        // out_t = z @ Wmu^T + bmu  (waves 0..3; others run ahead to next gh, safe)
        if (w < 4) {
            f32x4 o = {};
            #pragma unroll
            for (int kk = 0; kk < H / 32; ++kk) {
                bf16x8 a = lds8(za + kk * 32);
                bf16x8 b = g8<F32>(Wmu, WmuP + kk * 32);
                o = MFMA16(a, b, o);
            }
            #pragma unroll
            for (int r = 0; r < 4; ++r) {
                float vv = o[r] + bmuv;
                const size_t oi = outBase + (size_t)r * (LSTEPS * CO) + t * CO;
                if constexpr (F32) ((float*)out)[oi] = vv;
                else               ((__hip_bfloat16*)out)[oi] = __float2bfloat16(vv);
            }
        }
    }
}

__global__ __launch_bounds__(512, 2) void comm_out_fused(
    const void* hw,
    const void* Wlin, const void* blin,
    const void* g1,   const void* be1, const void* m1, const void* v1, const void* a1,
    const void* Wih,  const void* Whh, const void* bih, const void* bhh,
    const void* g2,   const void* be2, const void* m2, const void* v2, const void* a2,
    const void* Wc,   const void* bc,
    const void* g3,   const void* be3, const void* m3, const void* v3, const void* a3,
    const void* Wmu,  const void* bmu,
    void* out, const int* flag)
{
    __shared__ __align__(16) unsigned short h_lds[BM * LDP];  // h_t (bf16) for next-step A-frags
    __shared__ __align__(16) unsigned short u_lds[BM * LDP];  // x, then y_t, then z_t

    if (*flag) {
        pipeline<true>(hw, Wlin, blin, g1, be1, m1, v1, a1,
                       Wih, Whh, bih, bhh, g2, be2, m2, v2, a2,
                       Wc, bc, g3, be3, m3, v3, a3, Wmu, bmu,
                       out, h_lds, u_lds);
    } else {
        pipeline<false>(hw, Wlin, blin, g1, be1, m1, v1, a1,
                        Wih, Whh, bih, bhh, g2, be2, m2, v2, a2,
                        Wc, bc, g3, be3, m3, v3, a3, Wmu, bmu,
                        out, h_lds, u_lds);
    }
}

extern "C" void kernel_launch(void* const* d_in, const int* in_sizes, int n_in,
                              void* d_out, int out_size, void* d_ws, size_t ws_size,
                              hipStream_t stream) {
    (void)in_sizes; (void)n_in; (void)out_size; (void)ws_size;
    int* flag = (int*)d_ws;
    detect_dtype<<<dim3(1), dim3(1), 0, stream>>>(d_in[6], flag);
    comm_out_fused<<<dim3(8192 / BM), dim3(512), 0, stream>>>(
        d_in[0], d_in[1], d_in[2], d_in[3], d_in[4], d_in[5], d_in[6], d_in[7],
        d_in[8], d_in[9], d_in[10], d_in[11], d_in[12], d_in[13], d_in[14], d_in[15],
        d_in[16], d_in[17], d_in[18], d_in[19], d_in[20], d_in[21], d_in[22], d_in[23],
        d_in[24], d_in[25], d_out, flag);
}

// Round 3
// 727.505 us; speedup vs baseline: 1.1341x; 1.1341x over previous
//
#include <hip/hip_runtime.h>
#include <hip/hip_bf16.h>

// Fused Comm_OUT pipeline, batch-row-parallel (GRU recurrence is per-row).
// Fast path: weights pre-packed to bf16 fragment-streams in d_ws (prepass
// kernel), BM=16 rows/block, 512 blocks (2 blocks/CU), 8 waves/block.
// Fallback (ws too small): round-1 kernel (BM=32, direct weight reads).
// Runtime dtype detection: inputs may be fp32 or bf16.

typedef __attribute__((ext_vector_type(8))) short bf16x8;   // 8 x bf16 (4 VGPRs)
typedef __attribute__((ext_vector_type(4))) float f32x4;    // MFMA accumulator

#define MFMA16(a, b, c) __builtin_amdgcn_mfma_f32_16x16x32_bf16((a), (b), (c), 0, 0, 0)

constexpr int F   = 640;
constexpr int H   = 256;
constexpr int LSTEPS = 20;
constexpr int CO  = 32;
constexpr int LDP = 264;   // padded bf16 row stride

// packed-weight element offsets inside d_ws (after 1024-byte header)
constexpr size_t WHH_E  = 0;                    // 8w*3g*8kk*2j*64lane*8 = 196608
constexpr size_t WIH_E  = 196608;               // 196608
constexpr size_t WC_E   = 393216;               // 8w*8kk*2j*64*8       = 65536
constexpr size_t WMU_E  = 458752;               // 2w*8kk*64*8          = 8192
constexpr size_t WLIN_E = 466944;               // 8w*20kk*2j*64*8      = 163840
constexpr size_t PK_ELEMS = 630784;
constexpr size_t WS_NEEDED = 1024 + PK_ELEMS * 2;   // 1,262,592 B

__device__ __forceinline__ float bf2f(__hip_bfloat16 x) { return __bfloat162float(x); }
__device__ __forceinline__ unsigned short f2bs(float f) {
    __hip_bfloat16 h = __float2bfloat16(f);
    return *reinterpret_cast<unsigned short*>(&h);
}
__device__ __forceinline__ bf16x8 lds8(const unsigned short* p) {
    return *reinterpret_cast<const bf16x8*>(p);
}
__device__ __forceinline__ bf16x8 pk8(const unsigned short* base, size_t eoff) {
    return *reinterpret_cast<const bf16x8*>(base + eoff);
}
__device__ __forceinline__ float sigm(float x) {
    return 1.0f / (1.0f + __expf(-x));
}

// load 8 contiguous elements as a bf16 MFMA fragment (dtype-templated)
template<bool F32>
__device__ __forceinline__ bf16x8 g8(const void* base, size_t off) {
    if constexpr (!F32) {
        return *reinterpret_cast<const bf16x8*>((const __hip_bfloat16*)base + off);
    } else {
        const float* f = (const float*)base + off;
        float4 lo = *reinterpret_cast<const float4*>(f);
        float4 hi = *reinterpret_cast<const float4*>(f + 4);
        bf16x8 r;
        r[0] = (short)f2bs(lo.x); r[1] = (short)f2bs(lo.y);
        r[2] = (short)f2bs(lo.z); r[3] = (short)f2bs(lo.w);
        r[4] = (short)f2bs(hi.x); r[5] = (short)f2bs(hi.y);
        r[6] = (short)f2bs(hi.z); r[7] = (short)f2bs(hi.w);
        return r;
    }
}

template<bool F32>
__device__ __forceinline__ float ld1(const void* base, int i) {
    if constexpr (!F32) return bf2f(((const __hip_bfloat16*)base)[i]);
    else                return ((const float*)base)[i];
}

// ---------------- dtype detect: v1 (uniform[0.5,1.5]) ----------------
__global__ void detect_dtype(const void* v1, int* flag) {
    const unsigned short* u = (const unsigned short*)v1;
    int f32 = 0;
    for (int i = 0; i < 8; ++i) {
        unsigned short s = u[i];
        __hip_bfloat16 h = *reinterpret_cast<__hip_bfloat16*>(&s);
        float v = __bfloat162float(h);
        if (!(v >= 0.25f && v <= 2.0f)) f32 = 1;
    }
    *flag = f32;
}

// ---------------- weight pre-pack (fp32|bf16 -> bf16 fragment streams) ----------------
__device__ __forceinline__ unsigned short cvt1(const void* p, size_t i, bool f32) {
    if (f32) return f2bs(((const float*)p)[i]);
    return ((const unsigned short*)p)[i];
}

__global__ void prepack(const void* Wlin, const void* Wih, const void* Whh,
                        const void* Wc, const void* Wmu, const int* flag,
                        unsigned short* dst) {
    const bool f32 = (*flag != 0);
    const int gid = blockIdx.x * 256 + threadIdx.x;
    const void* src;
    size_t dbase;
    int row, col0, ncols;
    if (gid < 24576) {                       // Whh [768,256]
        int idx = gid;
        int lane = idx & 63, j = (idx >> 6) & 1, kk = (idx >> 7) & 7;
        int t2 = idx >> 10, g = t2 % 3, w = t2 / 3;
        row = g * 256 + w * 32 + j * 16 + (lane & 15);
        col0 = kk * 32 + (lane >> 4) * 8;
        ncols = 256; src = Whh; dbase = WHH_E + (size_t)idx * 8;
    } else if (gid < 49152) {                // Wih [768,256]
        int idx = gid - 24576;
        int lane = idx & 63, j = (idx >> 6) & 1, kk = (idx >> 7) & 7;
        int t2 = idx >> 10, g = t2 % 3, w = t2 / 3;
        row = g * 256 + w * 32 + j * 16 + (lane & 15);
        col0 = kk * 32 + (lane >> 4) * 8;
        ncols = 256; src = Wih; dbase = WIH_E + (size_t)idx * 8;
    } else if (gid < 57344) {                // Wc [256,256]
        int idx = gid - 49152;
        int lane = idx & 63, j = (idx >> 6) & 1, kk = (idx >> 7) & 7, w = idx >> 10;
        row = w * 32 + j * 16 + (lane & 15);
        col0 = kk * 32 + (lane >> 4) * 8;
        ncols = 256; src = Wc; dbase = WC_E + (size_t)idx * 8;
    } else if (gid < 58368) {                // Wmu [32,256], waves 0..1
        int idx = gid - 57344;
        int lane = idx & 63, kk = (idx >> 6) & 7, w = idx >> 9;
        row = w * 16 + (lane & 15);
        col0 = kk * 32 + (lane >> 4) * 8;
        ncols = 256; src = Wmu; dbase = WMU_E + (size_t)idx * 8;
    } else if (gid < 78848) {                // Wlin [256,640]
        int idx = gid - 58368;
        int lane = idx & 63, j = (idx >> 6) & 1;
        int t1 = idx >> 7, kk = t1 % 20, w = t1 / 20;
        row = w * 32 + j * 16 + (lane & 15);
        col0 = kk * 32 + (lane >> 4) * 8;
        ncols = 640; src = Wlin; dbase = WLIN_E + (size_t)idx * 8;
    } else {
        return;
    }
    const size_t s0 = (size_t)row * ncols + col0;
    #pragma unroll
    for (int i = 0; i < 8; ++i) dst[dbase + i] = cvt1(src, s0 + i, f32);
}

// ---------------- FAST PATH: BM=16, 512 blocks, packed weights ----------------
template<bool F32>
__device__ __forceinline__ void fast_pipe(
    const void* hw, const void* blin,
    const void* g1, const void* be1, const void* m1, const void* v1, const void* a1,
    const void* bih, const void* bhh,
    const void* g2, const void* be2, const void* m2, const void* v2, const void* a2,
    const void* bc,
    const void* g3, const void* be3, const void* m3, const void* v3, const void* a3,
    const void* bmu,
    const unsigned short* Wpk, void* out,
    unsigned short* h_lds, unsigned short* u_lds)
{
    const int tid  = threadIdx.x;
    const int w    = tid >> 6;
    const int lane = tid & 63;
    const int m16  = lane & 15;
    const int q    = lane >> 4;
    const int row0 = blockIdx.x * 16;
    const int c0 = w * 32 + m16;
    const int c1 = c0 + 16;
    const int cc2[2] = { c0, c1 };
    const size_t lane8 = (size_t)lane * 8;

    // persistent per-step params (folded)
    float s2v[2], t2v[2], s3v[2], t3f[2], bhhn[2];
    #pragma unroll
    for (int j = 0; j < 2; ++j) {
        const int cc = cc2[j];
        float s;
        s = ld1<F32>(g2, cc) * rsqrtf(ld1<F32>(v2, cc) + 1e-5f);
        s2v[j] = s; t2v[j] = ld1<F32>(be2, cc) - ld1<F32>(m2, cc) * s;
        s = ld1<F32>(g3, cc) * rsqrtf(ld1<F32>(v3, cc) + 1e-5f);
        s3v[j] = s;
        t3f[j] = (ld1<F32>(bc, cc) - ld1<F32>(m3, cc)) * s + ld1<F32>(be3, cc);
        bhhn[j] = ld1<F32>(bhh, 2 * H + cc);
    }
    const float a2v = ld1<F32>(a2, 0), a3v = ld1<F32>(a3, 0);

    // ---- Phase 1: x = prelu(bn1(rows @ Wlin^T + blin)) -> u_lds ----
    {
        f32x4 xacc[2] = {};
        #pragma unroll 5
        for (int kk = 0; kk < F / 32; ++kk) {
            bf16x8 a = g8<F32>(hw, (size_t)(row0 + m16) * F + kk * 32 + q * 8);
            bf16x8 b0 = pk8(Wpk, WLIN_E + (size_t)((w * 20 + kk) * 2 + 0) * 512 + lane8);
            bf16x8 b1 = pk8(Wpk, WLIN_E + (size_t)((w * 20 + kk) * 2 + 1) * 512 + lane8);
            xacc[0] = MFMA16(a, b0, xacc[0]);
            xacc[1] = MFMA16(a, b1, xacc[1]);
        }
        #pragma unroll
        for (int j = 0; j < 2; ++j) {
            const int cc = cc2[j];
            float s = ld1<F32>(g1, cc) * rsqrtf(ld1<F32>(v1, cc) + 1e-5f);
            float t = ld1<F32>(be1, cc) - ld1<F32>(m1, cc) * s;
            float bl = ld1<F32>(blin, cc);
            float av = ld1<F32>(a1, 0);
            #pragma unroll
            for (int r = 0; r < 4; ++r) {
                float vv = (xacc[j][r] + bl) * s + t;
                vv = (vv >= 0.0f) ? vv : av * vv;
                u_lds[(q * 4 + r) * LDP + cc] = f2bs(vv);
            }
        }
    }
    __syncthreads();

    // ---- Phase 2: gi = x @ Wih^T + (bih + bhh[r,z])  (registers) ----
    f32x4 gi[3][2] = {};
    {
        #pragma unroll
        for (int kk = 0; kk < 8; ++kk) {
            bf16x8 a = lds8(u_lds + m16 * LDP + kk * 32 + q * 8);
            #pragma unroll
            for (int g = 0; g < 3; ++g)
                #pragma unroll
                for (int j = 0; j < 2; ++j) {
                    bf16x8 b = pk8(Wpk, WIH_E + (size_t)(((w * 3 + g) * 8 + kk) * 2 + j) * 512 + lane8);
                    gi[g][j] = MFMA16(a, b, gi[g][j]);
                }
        }
        #pragma unroll
        for (int g = 0; g < 3; ++g)
            #pragma unroll
            for (int j = 0; j < 2; ++j) {
                float bias = ld1<F32>(bih, g * H + cc2[j]);
                if (g < 2) bias += ld1<F32>(bhh, g * H + cc2[j]);
                #pragma unroll
                for (int r = 0; r < 4; ++r) gi[g][j][r] += bias;
            }
    }

    // ---- GRU loop + fused downstream ----
    float hreg[2][4] = {};
    const unsigned short* haP = h_lds + m16 * LDP + q * 8;
    const unsigned short* uaP = u_lds + m16 * LDP + q * 8;
    const float bmuv = (w < 2) ? ld1<F32>(bmu, w * 16 + m16) : 0.0f;

    #pragma unroll 1
    for (int t = 0; t < LSTEPS; ++t) {
        f32x4 gh[3][2] = {};
        if (t > 0) {
            #pragma unroll
            for (int kk = 0; kk < 8; ++kk) {
                bf16x8 a = lds8(haP + kk * 32);
                #pragma unroll
                for (int g = 0; g < 3; ++g)
                    #pragma unroll
                    for (int j = 0; j < 2; ++j) {
                        bf16x8 b = pk8(Wpk, WHH_E + (size_t)(((w * 3 + g) * 8 + kk) * 2 + j) * 512 + lane8);
                        gh[g][j] = MFMA16(a, b, gh[g][j]);
                    }
            }
        }
        // gates + h update + y = prelu(bn2(h))
        float yv[2][4];
        #pragma unroll
        for (int j = 0; j < 2; ++j)
            #pragma unroll
            for (int r = 0; r < 4; ++r) {
                float rr = sigm(gi[0][j][r] + gh[0][j][r]);
                float zz = sigm(gi[1][j][r] + gh[1][j][r]);
                float nin = gi[2][j][r] + rr * (gh[2][j][r] + bhhn[j]);
                float nn = 2.0f * sigm(2.0f * nin) - 1.0f;   // tanh
                float hh = (1.0f - zz) * nn + zz * hreg[j][r];
                hreg[j][r] = hh;
                float y = hh * s2v[j] + t2v[j];
                yv[j][r] = (y >= 0.0f) ? y : a2v * y;
            }
        __syncthreads();   // A: everyone done reading h_lds / u_lds
        #pragma unroll
        for (int j = 0; j < 2; ++j)
            #pragma unroll
            for (int r = 0; r < 4; ++r) {
                const int idx = (q * 4 + r) * LDP + cc2[j];
                h_lds[idx] = f2bs(hreg[j][r]);
                u_lds[idx] = f2bs(yv[j][r]);
            }
        __syncthreads();   // B: h/y visible

        // w2 = y @ Wc^T
        f32x4 w2[2] = {};
        #pragma unroll
        for (int kk = 0; kk < 8; ++kk) {
            bf16x8 a = lds8(uaP + kk * 32);
            #pragma unroll
            for (int j = 0; j < 2; ++j) {
                bf16x8 b = pk8(Wpk, WC_E + (size_t)((w * 8 + kk) * 2 + j) * 512 + lane8);
                w2[j] = MFMA16(a, b, w2[j]);
            }
        }
        float zv[2][4];
        #pragma unroll
        for (int j = 0; j < 2; ++j)
            #pragma unroll
            for (int r = 0; r < 4; ++r) {
                float z0 = w2[j][r] * s3v[j] + t3f[j];
                zv[j][r] = (z0 >= 0.0f) ? z0 : a3v * z0;
            }
        __syncthreads();   // C: everyone done reading y
        #pragma unroll
        for (int j = 0; j < 2; ++j)
            #pragma unroll
            for (int r = 0; r < 4; ++r)
                u_lds[(q * 4 + r) * LDP + cc2[j]] = f2bs(zv[j][r]);
        __syncthreads();   // D: z visible

        // out_t = z @ Wmu^T + bmu   (waves 0..1 own the two 16x16 col-tiles)
        if (w < 2) {
            f32x4 o = {};
            #pragma unroll
            for (int kk = 0; kk < 8; ++kk) {
                bf16x8 a = lds8(uaP + kk * 32);
                bf16x8 b = pk8(Wpk, WMU_E + (size_t)(w * 8 + kk) * 512 + lane8);
                o = MFMA16(a, b, o);
            }
            #pragma unroll
            for (int r = 0; r < 4; ++r) {
                float vv = o[r] + bmuv;
                const size_t oi = (size_t)(row0 + q * 4 + r) * (LSTEPS * CO) + t * CO + w * 16 + m16;
                if constexpr (F32) ((float*)out)[oi] = vv;
                else               ((__hip_bfloat16*)out)[oi] = __float2bfloat16(vv);
            }
        }
    }
}

__global__ __launch_bounds__(512, 4) void comm_fast(
    const void* hw, const void* blin,
    const void* g1, const void* be1, const void* m1, const void* v1, const void* a1,
    const void* bih, const void* bhh,
    const void* g2, const void* be2, const void* m2, const void* v2, const void* a2,
    const void* bc,
    const void* g3, const void* be3, const void* m3, const void* v3, const void* a3,
    const void* bmu,
    const unsigned short* Wpk, void* out, const int* flag)
{
    __shared__ __align__(16) unsigned short h_lds[16 * LDP];
    __shared__ __align__(16) unsigned short u_lds[16 * LDP];
    if (*flag) {
        fast_pipe<true >(hw, blin, g1, be1, m1, v1, a1, bih, bhh,
                         g2, be2, m2, v2, a2, bc, g3, be3, m3, v3, a3, bmu,
                         Wpk, out, h_lds, u_lds);
    } else {
        fast_pipe<false>(hw, blin, g1, be1, m1, v1, a1, bih, bhh,
                         g2, be2, m2, v2, a2, bc, g3, be3, m3, v3, a3, bmu,
                         Wpk, out, h_lds, u_lds);
    }
}

// ---------------- FALLBACK: round-1 kernel (BM=32, direct reads) ----------------
template<bool F32>
__device__ __forceinline__ void pipeline(
    const void* hw,
    const void* Wlin, const void* blin,
    const void* g1,   const void* be1, const void* m1, const void* v1, const void* a1,
    const void* Wih,  const void* Whh, const void* bih, const void* bhh,
    const void* g2,   const void* be2, const void* m2, const void* v2, const void* a2,
    const void* Wc,   const void* bc,
    const void* g3,   const void* be3, const void* m3, const void* v3, const void* a3,
    const void* Wmu,  const void* bmu,
    void* out,
    unsigned short* h_lds, unsigned short* u_lds)
{
    const int tid  = threadIdx.x;
    const int w    = tid >> 6;
    const int lane = tid & 63;
    const int m16  = lane & 15;
    const int q    = lane >> 4;
    const int row0 = blockIdx.x * 32;
    const int c0 = w * 32 + m16;
    const int c1 = c0 + 16;
    const int cc2[2] = { c0, c1 };

    float s1v[2], t1v[2], s2v[2], t2v[2], s3v[2], t3v[2];
    float blv[2], bihv[3][2], bhhv[3][2], bcv[2];
    #pragma unroll
    for (int j = 0; j < 2; ++j) {
        const int cc = cc2[j];
        float s;
        s = ld1<F32>(g1, cc) * rsqrtf(ld1<F32>(v1, cc) + 1e-5f);
        s1v[j] = s; t1v[j] = ld1<F32>(be1, cc) - ld1<F32>(m1, cc) * s;
        s = ld1<F32>(g2, cc) * rsqrtf(ld1<F32>(v2, cc) + 1e-5f);
        s2v[j] = s; t2v[j] = ld1<F32>(be2, cc) - ld1<F32>(m2, cc) * s;
        s = ld1<F32>(g3, cc) * rsqrtf(ld1<F32>(v3, cc) + 1e-5f);
        s3v[j] = s; t3v[j] = ld1<F32>(be3, cc) - ld1<F32>(m3, cc) * s;
        blv[j] = ld1<F32>(blin, cc);
        bcv[j] = ld1<F32>(bc, cc);
        #pragma unroll
        for (int g = 0; g < 3; ++g) {
            bihv[g][j] = ld1<F32>(bih, g * H + cc);
            bhhv[g][j] = ld1<F32>(bhh, g * H + cc);
        }
    }
    const float a1v = ld1<F32>(a1, 0), a2v = ld1<F32>(a2, 0), a3v = ld1<F32>(a3, 0);

    {
        f32x4 acc[2][2] = {};
        const size_t A0 = (size_t)(row0 + m16) * F + q * 8;
        const size_t A1 = A0 + (size_t)16 * F;
        const size_t B0 = (size_t)c0 * F + q * 8;
        const size_t B1 = (size_t)c1 * F + q * 8;
        #pragma unroll 4
        for (int kk = 0; kk < F / 32; ++kk) {
            bf16x8 a0 = g8<F32>(hw, A0 + kk * 32);
            bf16x8 a1f = g8<F32>(hw, A1 + kk * 32);
            bf16x8 b0 = g8<F32>(Wlin, B0 + kk * 32);
            bf16x8 b1 = g8<F32>(Wlin, B1 + kk * 32);
            acc[0][0] = MFMA16(a0, b0, acc[0][0]);
            acc[1][0] = MFMA16(a1f, b0, acc[1][0]);
            acc[0][1] = MFMA16(a0, b1, acc[0][1]);
            acc[1][1] = MFMA16(a1f, b1, acc[1][1]);
        }
        #pragma unroll
        for (int mt = 0; mt < 2; ++mt)
            #pragma unroll
            for (int j = 0; j < 2; ++j)
                #pragma unroll
                for (int r = 0; r < 4; ++r) {
                    float vv = acc[mt][j][r] + blv[j];
                    vv = vv * s1v[j] + t1v[j];
                    vv = (vv >= 0.0f) ? vv : a1v * vv;
                    u_lds[(mt * 16 + q * 4 + r) * LDP + cc2[j]] = f2bs(vv);
                }
    }
    __syncthreads();

    f32x4 gi[2][3][2] = {};
    {
        const unsigned short* xa0 = u_lds + m16 * LDP + q * 8;
        const unsigned short* xa1 = xa0 + 16 * LDP;
        #pragma unroll
        for (int kk = 0; kk < H / 32; ++kk) {
            bf16x8 a0 = lds8(xa0 + kk * 32);
            bf16x8 a1f = lds8(xa1 + kk * 32);
            #pragma unroll
            for (int g = 0; g < 3; ++g)
                #pragma unroll
                for (int j = 0; j < 2; ++j) {
                    bf16x8 b = g8<F32>(Wih, (size_t)(g * H + cc2[j]) * H + q * 8 + kk * 32);
                    gi[0][g][j] = MFMA16(a0, b, gi[0][g][j]);
                    gi[1][g][j] = MFMA16(a1f, b, gi[1][g][j]);
                }
        }
        #pragma unroll
        for (int mt = 0; mt < 2; ++mt)
            #pragma unroll
            for (int g = 0; g < 3; ++g)
                #pragma unroll
                for (int j = 0; j < 2; ++j)
                    #pragma unroll
                    for (int r = 0; r < 4; ++r)
                        gi[mt][g][j][r] += bihv[g][j];
    }

    float hreg[2][2][4] = {};
    const unsigned short* ha0 = h_lds + m16 * LDP + q * 8;
    const unsigned short* ha1 = ha0 + 16 * LDP;
    const unsigned short* ua0 = u_lds + m16 * LDP + q * 8;
    const unsigned short* ua1 = ua0 + 16 * LDP;
    const int mto = (w >> 1) & 1;
    const int nto = w & 1;
    const float bmuv = (w < 4) ? ld1<F32>(bmu, nto * 16 + m16) : 0.0f;
    const size_t outBase = (size_t)(row0 + mto * 16 + q * 4) * (LSTEPS * CO) + nto * 16 + m16;
    const unsigned short* za = u_lds + (mto * 16 + m16) * LDP + q * 8;

    #pragma unroll 1
    for (int t = 0; t < LSTEPS; ++t) {
        f32x4 gh[2][3][2] = {};
        if (t > 0) {
            #pragma unroll
            for (int kk = 0; kk < H / 32; ++kk) {
                bf16x8 a0 = lds8(ha0 + kk * 32);
                bf16x8 a1f = lds8(ha1 + kk * 32);
                #pragma unroll
                for (int g = 0; g < 3; ++g)
                    #pragma unroll
                    for (int j = 0; j < 2; ++j) {
                        bf16x8 b = g8<F32>(Whh, (size_t)(g * H + cc2[j]) * H + q * 8 + kk * 32);
                        gh[0][g][j] = MFMA16(a0, b, gh[0][g][j]);
                        gh[1][g][j] = MFMA16(a1f, b, gh[1][g][j]);
                    }
            }
        }
        float yv[2][2][4];
        #pragma unroll
        for (int mt = 0; mt < 2; ++mt)
            #pragma unroll
            for (int j = 0; j < 2; ++j)
                #pragma unroll
                for (int r = 0; r < 4; ++r) {
                    float rr = sigm(gi[mt][0][j][r] + gh[mt][0][j][r] + bhhv[0][j]);
                    float zz = sigm(gi[mt][1][j][r] + gh[mt][1][j][r] + bhhv[1][j]);
                    float nin = gi[mt][2][j][r] + rr * (gh[mt][2][j][r] + bhhv[2][j]);
                    float nn = 2.0f * sigm(2.0f * nin) - 1.0f;
                    float hh = (1.0f - zz) * nn + zz * hreg[mt][j][r];
                    hreg[mt][j][r] = hh;
                    float y = hh * s2v[j] + t2v[j];
                    yv[mt][j][r] = (y >= 0.0f) ? y : a2v * y;
                }
        __syncthreads();
        #pragma unroll
        for (int mt = 0; mt < 2; ++mt)
            #pragma unroll
            for (int j = 0; j < 2; ++j)
                #pragma unroll
                for (int r = 0; r < 4; ++r) {
                    const int idx = (mt * 16 + q * 4 + r) * LDP + cc2[j];
                    h_lds[idx] = f2bs(hreg[mt][j][r]);
                    u_lds[idx] = f2bs(yv[mt][j][r]);
                }
        __syncthreads();

        f32x4 w2[2][2] = {};
        #pragma unroll
        for (int kk = 0; kk < H / 32; ++kk) {
            bf16x8 a0 = lds8(ua0 + kk * 32);
            bf16x8 a1f = lds8(ua1 + kk * 32);
            #pragma unroll
            for (int j = 0; j < 2; ++j) {
                bf16x8 b = g8<F32>(Wc, (size_t)cc2[j] * H + q * 8 + kk * 32);
                w2[0][j] = MFMA16(a0, b, w2[0][j]);
                w2[1][j] = MFMA16(a1f, b, w2[1][j]);
            }
        }
        float zv[2][2][4];
        #pragma unroll
        for (int mt = 0; mt < 2; ++mt)
            #pragma unroll
            for (int j = 0; j < 2; ++j)
                #pragma unroll
                for (int r = 0; r < 4; ++r) {
                    float z0 = (w2[mt][j][r] + bcv[j]) * s3v[j] + t3v[j];
                    zv[mt][j][r] = (z0 >= 0.0f) ? z0 : a3v * z0;
                }
        __syncthreads();
        #pragma unroll
        for (int mt = 0; mt < 2; ++mt)
            #pragma unroll
            for (int j = 0; j < 2; ++j)
                #pragma unroll
                for (int r = 0; r < 4; ++r)
                    u_lds[(mt * 16 + q * 4 + r) * LDP + cc2[j]] = f2bs(zv[mt][j][r]);
        __syncthreads();

        if (w < 4) {
            f32x4 o = {};
            #pragma unroll
            for (int kk = 0; kk < H / 32; ++kk) {
                bf16x8 a = lds8(za + kk * 32);
                bf16x8 b = g8<F32>(Wmu, (size_t)(nto * 16 + m16) * H + q * 8 + kk * 32);
                o = MFMA16(a, b, o);
            }
            #pragma unroll
            for (int r = 0; r < 4; ++r) {
                float vv = o[r] + bmuv;
                const size_t oi = outBase + (size_t)r * (LSTEPS * CO) + t * CO;
                if constexpr (F32) ((float*)out)[oi] = vv;
                else               ((__hip_bfloat16*)out)[oi] = __float2bfloat16(vv);
            }
        }
    }
}

__global__ __launch_bounds__(512, 2) void comm_out_fused(
    const void* hw,
    const void* Wlin, const void* blin,
    const void* g1,   const void* be1, const void* m1, const void* v1, const void* a1,
    const void* Wih,  const void* Whh, const void* bih, const void* bhh,
    const void* g2,   const void* be2, const void* m2, const void* v2, const void* a2,
    const void* Wc,   const void* bc,
    const void* g3,   const void* be3, const void* m3, const void* v3, const void* a3,
    const void* Wmu,  const void* bmu,
    void* out, const int* flag)
{
    __shared__ __align__(16) unsigned short h_lds[32 * LDP];
    __shared__ __align__(16) unsigned short u_lds[32 * LDP];
    if (*flag) {
        pipeline<true>(hw, Wlin, blin, g1, be1, m1, v1, a1,
                       Wih, Whh, bih, bhh, g2, be2, m2, v2, a2,
                       Wc, bc, g3, be3, m3, v3, a3, Wmu, bmu,
                       out, h_lds, u_lds);
    } else {
        pipeline<false>(hw, Wlin, blin, g1, be1, m1, v1, a1,
                        Wih, Whh, bih, bhh, g2, be2, m2, v2, a2,
                        Wc, bc, g3, be3, m3, v3, a3, Wmu, bmu,
                        out, h_lds, u_lds);
    }
}

extern "C" void kernel_launch(void* const* d_in, const int* in_sizes, int n_in,
                              void* d_out, int out_size, void* d_ws, size_t ws_size,
                              hipStream_t stream) {
    (void)in_sizes; (void)n_in; (void)out_size;
    int* flag = (int*)d_ws;
    detect_dtype<<<dim3(1), dim3(1), 0, stream>>>(d_in[6], flag);

    if (ws_size >= WS_NEEDED) {
        unsigned short* Wpk = (unsigned short*)((char*)d_ws + 1024);
        prepack<<<dim3(308), dim3(256), 0, stream>>>(
            d_in[1], d_in[8], d_in[9], d_in[17], d_in[24], flag, Wpk);
        comm_fast<<<dim3(512), dim3(512), 0, stream>>>(
            d_in[0], d_in[2],
            d_in[3], d_in[4], d_in[5], d_in[6], d_in[7],
            d_in[10], d_in[11],
            d_in[12], d_in[13], d_in[14], d_in[15], d_in[16],
            d_in[18],
            d_in[19], d_in[20], d_in[21], d_in[22], d_in[23],
            d_in[25],
            Wpk, d_out, flag);
    } else {
        comm_out_fused<<<dim3(256), dim3(512), 0, stream>>>(
            d_in[0], d_in[1], d_in[2], d_in[3], d_in[4], d_in[5], d_in[6], d_in[7],
            d_in[8], d_in[9], d_in[10], d_in[11], d_in[12], d_in[13], d_in[14], d_in[15],
            d_in[16], d_in[17], d_in[18], d_in[19], d_in[20], d_in[21], d_in[22], d_in[23],
            d_in[24], d_in[25], d_out, flag);
    }
}